// Round 1
// baseline (4471.909 us; speedup 1.0000x reference)
//
#include <hip/hip_runtime.h>

// ---------------------------------------------------------------------------
// GCN 2-layer forward, f32.
//   norm_out = outdeg(src)^-1/2 (clamp>=1), norm_in = indeg(dst)^-1/2
//   L1 (IN<HID): agg1 = scatter_add((h*norm_out)[src] -> dst);
//                h1  = relu(agg1@W1 * norm_in + b1); h1n = h1*norm_out
//   L2 (HID>OUT): h2 = h1n@W2; out = scatter_add(h2[src]->dst)*norm_in + b2
// ---------------------------------------------------------------------------

__global__ __launch_bounds__(256)
void degree_hist(const int* __restrict__ src, const int* __restrict__ dst,
                 float* __restrict__ deg_out, float* __restrict__ deg_in, int E)
{
    int e = blockIdx.x * 256 + threadIdx.x;
    if (e < E) {
        unsafeAtomicAdd(&deg_out[src[e]], 1.0f);
        unsafeAtomicAdd(&deg_in[dst[e]], 1.0f);
    }
}

__global__ __launch_bounds__(256)
void norm_finalize(float* __restrict__ a, int n2)
{
    int i = blockIdx.x * 256 + threadIdx.x;
    if (i < n2) {
        float d = fmaxf(a[i], 1.0f);
        a[i] = 1.0f / sqrtf(d);   // accurate rsqrt (matches f32 ref closely)
    }
}

// scatter_add of CH-float rows: acc[dst[e]] += X[src[e]] * (SCALE? nrm[src[e]] : 1)
template<int CH, bool SCALE>
__global__ __launch_bounds__(256)
void scatter_accum(const float* __restrict__ X, const int* __restrict__ src,
                   const int* __restrict__ dst, const float* __restrict__ nrm,
                   float* __restrict__ acc, int E)
{
    constexpr int LPE = CH / 4;                 // lanes per edge (float4 each)
    int t = blockIdx.x * 256 + threadIdx.x;
    int e = t / LPE;
    int lane = t % LPE;
    if (e >= E) return;
    int s = src[e], d = dst[e];
    float4 v = *(const float4*)(X + (size_t)s * CH + lane * 4);
    if (SCALE) {
        float w = nrm[s];
        v.x *= w; v.y *= w; v.z *= w; v.w *= w;
    }
    float* ap = acc + (size_t)d * CH + lane * 4;
    unsafeAtomicAdd(ap + 0, v.x);
    unsafeAtomicAdd(ap + 1, v.y);
    unsafeAtomicAdd(ap + 2, v.z);
    unsafeAtomicAdd(ap + 3, v.w);
}

// Tiled f32 GEMM: C[M,NC] = A[M,K] @ B[K,NC], BM=BN=64, BK=32, 256 thr, 4x4/thr.
// EPI==0: C = relu(C*norm_in[row] + bias[col]) * norm_out[row]   (layer-1)
// EPI==1: plain store                                            (layer-2 proj)
template<int EPI>
__global__ __launch_bounds__(256)
void gemm_tiled(const float* __restrict__ A, const float* __restrict__ B,
                float* __restrict__ C, int M, int K, int NC,
                const float* __restrict__ norm_in,
                const float* __restrict__ norm_out,
                const float* __restrict__ bias)
{
    __shared__ float As[32][68];   // [k][row], padded 64->68 (16B-aligned rows)
    __shared__ float Bs[32][64];   // [k][col]
    const int tid = threadIdx.x;
    const int tx = tid & 15;       // col group (4 cols)
    const int ty = tid >> 4;       // row group (4 rows)
    const int brow = blockIdx.x * 64;
    const int bcol = blockIdx.y * 64;

    const int ar = tid >> 2;          // 0..63  A-stage row
    const int ak = (tid & 3) * 8;     // 0,8,16,24  A-stage k base (8 floats)
    const int bk = tid >> 3;          // 0..31  B-stage k row
    const int bc = (tid & 7) * 8;     // 0..56  B-stage col base (8 floats)

    float acc[4][4] = {};

    for (int k0 = 0; k0 < K; k0 += 32) {
        // stage A (transposed into LDS)
        {
            int grow = brow + ar;
            float4 v0 = make_float4(0.f, 0.f, 0.f, 0.f), v1 = v0;
            if (grow < M) {
                const float* ap = A + (size_t)grow * K + (k0 + ak);
                v0 = *(const float4*)ap;
                v1 = *(const float4*)(ap + 4);
            }
            As[ak + 0][ar] = v0.x; As[ak + 1][ar] = v0.y;
            As[ak + 2][ar] = v0.z; As[ak + 3][ar] = v0.w;
            As[ak + 4][ar] = v1.x; As[ak + 5][ar] = v1.y;
            As[ak + 6][ar] = v1.z; As[ak + 7][ar] = v1.w;
        }
        // stage B
        {
            const float* bp = B + (size_t)(k0 + bk) * NC + (bcol + bc);
            *(float4*)&Bs[bk][bc]     = *(const float4*)bp;
            *(float4*)&Bs[bk][bc + 4] = *(const float4*)(bp + 4);
        }
        __syncthreads();
        #pragma unroll
        for (int k = 0; k < 32; ++k) {
            float4 a = *(const float4*)&As[k][ty * 4];
            float4 b = *(const float4*)&Bs[k][tx * 4];
            acc[0][0] = fmaf(a.x, b.x, acc[0][0]);
            acc[0][1] = fmaf(a.x, b.y, acc[0][1]);
            acc[0][2] = fmaf(a.x, b.z, acc[0][2]);
            acc[0][3] = fmaf(a.x, b.w, acc[0][3]);
            acc[1][0] = fmaf(a.y, b.x, acc[1][0]);
            acc[1][1] = fmaf(a.y, b.y, acc[1][1]);
            acc[1][2] = fmaf(a.y, b.z, acc[1][2]);
            acc[1][3] = fmaf(a.y, b.w, acc[1][3]);
            acc[2][0] = fmaf(a.z, b.x, acc[2][0]);
            acc[2][1] = fmaf(a.z, b.y, acc[2][1]);
            acc[2][2] = fmaf(a.z, b.z, acc[2][2]);
            acc[2][3] = fmaf(a.z, b.w, acc[2][3]);
            acc[3][0] = fmaf(a.w, b.x, acc[3][0]);
            acc[3][1] = fmaf(a.w, b.y, acc[3][1]);
            acc[3][2] = fmaf(a.w, b.z, acc[3][2]);
            acc[3][3] = fmaf(a.w, b.w, acc[3][3]);
        }
        __syncthreads();
    }

    const int col = bcol + tx * 4;
    #pragma unroll
    for (int r = 0; r < 4; ++r) {
        int row = brow + ty * 4 + r;
        if (row >= M) continue;
        float4 o = make_float4(acc[r][0], acc[r][1], acc[r][2], acc[r][3]);
        if (EPI == 0) {
            float ni = norm_in[row];
            float no = norm_out[row];
            o.x = fmaxf(fmaf(o.x, ni, bias[col + 0]), 0.0f) * no;
            o.y = fmaxf(fmaf(o.y, ni, bias[col + 1]), 0.0f) * no;
            o.z = fmaxf(fmaf(o.z, ni, bias[col + 2]), 0.0f) * no;
            o.w = fmaxf(fmaf(o.w, ni, bias[col + 3]), 0.0f) * no;
        }
        *(float4*)(C + (size_t)row * NC + col) = o;
    }
}

__global__ __launch_bounds__(256)
void out_finalize(float* __restrict__ out, const float* __restrict__ norm_in,
                  const float* __restrict__ bias, int N, int OUT)
{
    int c4 = OUT / 4;
    int t = blockIdx.x * 256 + threadIdx.x;
    if (t >= N * c4) return;
    int i = t / c4;
    int c = (t % c4) * 4;
    float ni = norm_in[i];
    float* p = out + (size_t)i * OUT + c;
    float4 v = *(float4*)p;
    v.x = fmaf(v.x, ni, bias[c + 0]);
    v.y = fmaf(v.y, ni, bias[c + 1]);
    v.z = fmaf(v.z, ni, bias[c + 2]);
    v.w = fmaf(v.w, ni, bias[c + 3]);
    *(float4*)p = v;
}

extern "C" void kernel_launch(void* const* d_in, const int* in_sizes, int n_in,
                              void* d_out, int out_size, void* d_ws, size_t ws_size,
                              hipStream_t stream)
{
    const float* h   = (const float*)d_in[0];
    const int*   src = (const int*)d_in[1];
    const int*   dst = (const int*)d_in[2];
    const float* W1  = (const float*)d_in[3];
    const float* b1  = (const float*)d_in[4];
    const float* W2  = (const float*)d_in[5];
    const float* b2  = (const float*)d_in[6];
    float* out = (float*)d_out;

    const int HID = in_sizes[4];            // 256
    const int OUT = in_sizes[6];            // 64
    const int IN  = in_sizes[3] / HID;      // 128
    const int N   = in_sizes[0] / IN;       // 100000
    const int E   = in_sizes[1];            // 1600000

    // workspace layout (floats): [norm_out N][norm_in N][agg1 N*IN][h1n N*HID]
    float* ws       = (float*)d_ws;
    float* norm_out = ws;
    float* norm_in  = ws + N;
    float* agg1     = ws + 2 * (size_t)N;
    float* h1n      = agg1 + (size_t)N * IN;
    float* h2       = agg1;                 // reuse agg1 region for h2 [N,OUT]

    // zero norms + agg1 (contiguous) and d_out (atomic targets)
    hipMemsetAsync(ws, 0, (size_t)(2 + IN) * N * sizeof(float), stream);
    hipMemsetAsync(d_out, 0, (size_t)N * OUT * sizeof(float), stream);

    // degrees -> norms
    degree_hist<<<(E + 255) / 256, 256, 0, stream>>>(src, dst, norm_out, norm_in, E);
    norm_finalize<<<(2 * N + 255) / 256, 256, 0, stream>>>(ws, 2 * N);

    // layer-1 aggregation: agg1[dst] += h[src] * norm_out[src]
    {
        size_t threads = (size_t)E * (IN / 4);
        scatter_accum<128, true><<<(threads + 255) / 256, 256, 0, stream>>>(
            h, src, dst, norm_out, agg1, E);
    }

    // layer-1 projection + epilogue (relu, norms, bias), pre-scaled by norm_out
    gemm_tiled<0><<<dim3((N + 63) / 64, HID / 64), 256, 0, stream>>>(
        agg1, W1, h1n, N, IN, HID, norm_in, norm_out, b1);

    // layer-2 projection
    gemm_tiled<1><<<dim3((N + 63) / 64, OUT / 64), 256, 0, stream>>>(
        h1n, W2, h2, N, HID, OUT, nullptr, nullptr, nullptr);

    // layer-2 aggregation into d_out
    {
        size_t threads = (size_t)E * (OUT / 4);
        scatter_accum<64, false><<<(threads + 255) / 256, 256, 0, stream>>>(
            h2, src, dst, nullptr, out, E);
    }

    // out = out*norm_in + b2
    out_finalize<<<((N * (OUT / 4)) + 255) / 256, 256, 0, stream>>>(
        out, norm_in, b2, N, OUT);
}

// Round 2
// 752.159 us; speedup vs baseline: 5.9454x; 5.9454x over previous
//
#include <hip/hip_runtime.h>

// ---------------------------------------------------------------------------
// GCN 2-layer forward, f32 — CSR-gather version (no float atomics).
//   1. int histogram of src/dst degrees
//   2. exclusive scan of deg_in -> row_start (dst-CSR)
//   3. fill perm[]: edge srcs grouped by dst
//   4. gather-aggregate L1: agg1[n] = sum_{e in in(n)} h[src_e]*norm_out[src_e]
//   5. GEMM1 + epilogue relu(x*norm_in+b1)*norm_out
//   6. GEMM2 (project first: HID>OUT)
//   7. gather-aggregate L2 + fused *norm_in + b2 -> d_out
// ---------------------------------------------------------------------------

__global__ __launch_bounds__(256)
void hist_int(const int* __restrict__ src, const int* __restrict__ dst,
              int* __restrict__ deg_out, int* __restrict__ deg_in, int E)
{
    int e = blockIdx.x * 256 + threadIdx.x;
    if (e < E) {
        atomicAdd(&deg_out[src[e]], 1);
        atomicAdd(&deg_in[dst[e]], 1);
    }
}

// ---- 3-kernel exclusive scan over deg_in (chunk = 1024 elems/block) -------
__global__ __launch_bounds__(256)
void scan_block_sums(const int* __restrict__ deg, int* __restrict__ blockSums, int N)
{
    int t = threadIdx.x;
    int base = blockIdx.x * 1024 + t * 4;
    int s = 0;
    #pragma unroll
    for (int i = 0; i < 4; ++i) { int idx = base + i; if (idx < N) s += deg[idx]; }
    #pragma unroll
    for (int d = 32; d > 0; d >>= 1) s += __shfl_down(s, d);
    __shared__ int ws[4];
    int wid = t >> 6, lane = t & 63;
    if (lane == 0) ws[wid] = s;
    __syncthreads();
    if (t == 0) blockSums[blockIdx.x] = ws[0] + ws[1] + ws[2] + ws[3];
}

__global__ void scan_offsets(const int* __restrict__ blockSums, int* __restrict__ blockOffs,
                             int NB, int* __restrict__ row_start, int N, int E)
{
    if (threadIdx.x == 0 && blockIdx.x == 0) {
        int run = 0;
        for (int b = 0; b < NB; ++b) { blockOffs[b] = run; run += blockSums[b]; }
        row_start[N] = E;
    }
}

__global__ __launch_bounds__(256)
void scan_write(const int* __restrict__ deg, const int* __restrict__ blockOffs,
                int* __restrict__ row_start, int* __restrict__ cursor, int N)
{
    int t = threadIdx.x, lane = t & 63, wid = t >> 6;
    int base = blockIdx.x * 1024 + t * 4;
    int v[4]; int s = 0;
    #pragma unroll
    for (int i = 0; i < 4; ++i) {
        int idx = base + i;
        v[i] = (idx < N) ? deg[idx] : 0;
        s += v[i];
    }
    int x = s;                                   // inclusive wave scan
    #pragma unroll
    for (int d = 1; d < 64; d <<= 1) { int y = __shfl_up(x, d); if (lane >= d) x += y; }
    __shared__ int wtot[4];
    if (lane == 63) wtot[wid] = x;
    __syncthreads();
    int woff = 0;
    for (int w = 0; w < wid; ++w) woff += wtot[w];
    int run = (x - s) + woff + blockOffs[blockIdx.x];
    #pragma unroll
    for (int i = 0; i < 4; ++i) {
        int idx = base + i;
        if (idx < N) { row_start[idx] = run; cursor[idx] = run; run += v[i]; }
    }
}

__global__ __launch_bounds__(256)
void fill_perm(const int* __restrict__ src, const int* __restrict__ dst,
               int* __restrict__ cursor, int* __restrict__ perm, int E)
{
    int e = blockIdx.x * 256 + threadIdx.x;
    if (e < E) {
        int pos = atomicAdd(&cursor[dst[e]], 1);
        perm[pos] = src[e];
    }
}

// in-place int degree -> d^{-1/2} float (clamp >= 1)
__global__ __launch_bounds__(256)
void norm_finalize(int* __restrict__ deg, float* __restrict__ nrm, int n)
{
    int i = blockIdx.x * 256 + threadIdx.x;
    if (i < n) {
        int d = deg[i];
        float df = (float)(d > 1 ? d : 1);
        nrm[i] = 1.0f / sqrtf(df);
    }
}

// one wave per dst node, 128 ch (float2/lane): agg = sum h[src]*norm_out[src]
__global__ __launch_bounds__(256)
void gather_agg128(const float* __restrict__ X, const int* __restrict__ perm,
                   const int* __restrict__ row_start, const float* __restrict__ norm_out,
                   float* __restrict__ out, int N)
{
    int wid = threadIdx.x >> 6, lane = threadIdx.x & 63;
    int n = blockIdx.x * 4 + wid;
    if (n >= N) return;
    int e = row_start[n], e1 = row_start[n + 1];
    const float2* X2 = (const float2*)X;
    float2 acc = make_float2(0.f, 0.f);
    for (; e + 1 < e1; e += 2) {
        int a = perm[e], b = perm[e + 1];
        float wa = norm_out[a], wb = norm_out[b];
        float2 va = X2[(size_t)a * 64 + lane];
        float2 vb = X2[(size_t)b * 64 + lane];
        acc.x += va.x * wa + vb.x * wb;
        acc.y += va.y * wa + vb.y * wb;
    }
    if (e < e1) {
        int a = perm[e];
        float wa = norm_out[a];
        float2 va = X2[(size_t)a * 64 + lane];
        acc.x += va.x * wa;
        acc.y += va.y * wa;
    }
    ((float2*)out)[(size_t)n * 64 + lane] = acc;
}

// one wave per dst node, 64 ch (1 float/lane); fused *norm_in + bias epilogue
__global__ __launch_bounds__(256)
void gather_out64(const float* __restrict__ X, const int* __restrict__ perm,
                  const int* __restrict__ row_start, const float* __restrict__ norm_in,
                  const float* __restrict__ bias, float* __restrict__ out, int N)
{
    int wid = threadIdx.x >> 6, lane = threadIdx.x & 63;
    int n = blockIdx.x * 4 + wid;
    if (n >= N) return;
    int e = row_start[n], e1 = row_start[n + 1];
    float acc = 0.f;
    for (; e + 1 < e1; e += 2) {
        int a = perm[e], b = perm[e + 1];
        acc += X[(size_t)a * 64 + lane] + X[(size_t)b * 64 + lane];
    }
    if (e < e1) acc += X[(size_t)perm[e] * 64 + lane];
    out[(size_t)n * 64 + lane] = fmaf(acc, norm_in[n], bias[lane]);
}

// Tiled f32 GEMM: C[M,NC] = A[M,K] @ B[K,NC], BM=BN=64, BK=32, 256 thr, 4x4/thr.
// EPI==0: C = relu(C*norm_in[row] + bias[col]) * norm_out[row]   (layer-1)
// EPI==1: plain store                                            (layer-2 proj)
template<int EPI>
__global__ __launch_bounds__(256)
void gemm_tiled(const float* __restrict__ A, const float* __restrict__ B,
                float* __restrict__ C, int M, int K, int NC,
                const float* __restrict__ norm_in,
                const float* __restrict__ norm_out,
                const float* __restrict__ bias)
{
    __shared__ float As[32][68];
    __shared__ float Bs[32][64];
    const int tid = threadIdx.x;
    const int tx = tid & 15;
    const int ty = tid >> 4;
    const int brow = blockIdx.x * 64;
    const int bcol = blockIdx.y * 64;

    const int ar = tid >> 2;
    const int ak = (tid & 3) * 8;
    const int bk = tid >> 3;
    const int bc = (tid & 7) * 8;

    float acc[4][4] = {};

    for (int k0 = 0; k0 < K; k0 += 32) {
        {
            int grow = brow + ar;
            float4 v0 = make_float4(0.f, 0.f, 0.f, 0.f), v1 = v0;
            if (grow < M) {
                const float* ap = A + (size_t)grow * K + (k0 + ak);
                v0 = *(const float4*)ap;
                v1 = *(const float4*)(ap + 4);
            }
            As[ak + 0][ar] = v0.x; As[ak + 1][ar] = v0.y;
            As[ak + 2][ar] = v0.z; As[ak + 3][ar] = v0.w;
            As[ak + 4][ar] = v1.x; As[ak + 5][ar] = v1.y;
            As[ak + 6][ar] = v1.z; As[ak + 7][ar] = v1.w;
        }
        {
            const float* bp = B + (size_t)(k0 + bk) * NC + (bcol + bc);
            *(float4*)&Bs[bk][bc]     = *(const float4*)bp;
            *(float4*)&Bs[bk][bc + 4] = *(const float4*)(bp + 4);
        }
        __syncthreads();
        #pragma unroll
        for (int k = 0; k < 32; ++k) {
            float4 a = *(const float4*)&As[k][ty * 4];
            float4 b = *(const float4*)&Bs[k][tx * 4];
            acc[0][0] = fmaf(a.x, b.x, acc[0][0]);
            acc[0][1] = fmaf(a.x, b.y, acc[0][1]);
            acc[0][2] = fmaf(a.x, b.z, acc[0][2]);
            acc[0][3] = fmaf(a.x, b.w, acc[0][3]);
            acc[1][0] = fmaf(a.y, b.x, acc[1][0]);
            acc[1][1] = fmaf(a.y, b.y, acc[1][1]);
            acc[1][2] = fmaf(a.y, b.z, acc[1][2]);
            acc[1][3] = fmaf(a.y, b.w, acc[1][3]);
            acc[2][0] = fmaf(a.z, b.x, acc[2][0]);
            acc[2][1] = fmaf(a.z, b.y, acc[2][1]);
            acc[2][2] = fmaf(a.z, b.z, acc[2][2]);
            acc[2][3] = fmaf(a.z, b.w, acc[2][3]);
            acc[3][0] = fmaf(a.w, b.x, acc[3][0]);
            acc[3][1] = fmaf(a.w, b.y, acc[3][1]);
            acc[3][2] = fmaf(a.w, b.z, acc[3][2]);
            acc[3][3] = fmaf(a.w, b.w, acc[3][3]);
        }
        __syncthreads();
    }

    const int col = bcol + tx * 4;
    #pragma unroll
    for (int r = 0; r < 4; ++r) {
        int row = brow + ty * 4 + r;
        if (row >= M) continue;
        float4 o = make_float4(acc[r][0], acc[r][1], acc[r][2], acc[r][3]);
        if (EPI == 0) {
            float ni = norm_in[row];
            float no = norm_out[row];
            o.x = fmaxf(fmaf(o.x, ni, bias[col + 0]), 0.0f) * no;
            o.y = fmaxf(fmaf(o.y, ni, bias[col + 1]), 0.0f) * no;
            o.z = fmaxf(fmaf(o.z, ni, bias[col + 2]), 0.0f) * no;
            o.w = fmaxf(fmaf(o.w, ni, bias[col + 3]), 0.0f) * no;
        }
        *(float4*)(C + (size_t)row * NC + col) = o;
    }
}

extern "C" void kernel_launch(void* const* d_in, const int* in_sizes, int n_in,
                              void* d_out, int out_size, void* d_ws, size_t ws_size,
                              hipStream_t stream)
{
    const float* h   = (const float*)d_in[0];
    const int*   src = (const int*)d_in[1];
    const int*   dst = (const int*)d_in[2];
    const float* W1  = (const float*)d_in[3];
    const float* b1  = (const float*)d_in[4];
    const float* W2  = (const float*)d_in[5];
    const float* b2  = (const float*)d_in[6];
    float* out = (float*)d_out;

    const int HID = in_sizes[4];            // 256
    const int OUT = in_sizes[6];            // 64
    const int IN  = in_sizes[3] / HID;      // 128
    const int N   = in_sizes[0] / IN;       // 100000
    const int E   = in_sizes[1];            // 1600000
    const int NB  = (N + 1023) / 1024;      // scan blocks

    // workspace layout (256B-aligned chunks)
    char* p = (char*)d_ws;
    auto alloc = [&](size_t bytes) { void* r = p; p += (bytes + 255) & ~255ULL; return r; };
    int* deg_out   = (int*)alloc((size_t)N * 4);        // -> norm_out (in place)
    int* deg_in    = (int*)alloc((size_t)N * 4);        // -> norm_in  (in place)
    int* row_start = (int*)alloc((size_t)(N + 1) * 4);
    int* cursor    = (int*)alloc((size_t)N * 4);
    int* blockSums = (int*)alloc((size_t)NB * 4);
    int* blockOffs = (int*)alloc((size_t)NB * 4);
    int* perm      = (int*)alloc((size_t)E * 4);
    float* agg1    = (float*)alloc((size_t)N * IN * 4);
    float* h1n     = (float*)alloc((size_t)N * HID * 4);
    float* h2      = agg1;                              // reuse for [N,OUT]
    float* norm_out = (float*)deg_out;
    float* norm_in  = (float*)deg_in;

    // zero the two degree histograms (covers alignment gap too)
    hipMemsetAsync(deg_out, 0, (size_t)((char*)row_start - (char*)deg_out), stream);

    // 1. degrees
    hist_int<<<(E + 255) / 256, 256, 0, stream>>>(src, dst, deg_out, deg_in, E);

    // 2. exclusive scan deg_in -> row_start (+ cursor copy)
    scan_block_sums<<<NB, 256, 0, stream>>>(deg_in, blockSums, N);
    scan_offsets<<<1, 64, 0, stream>>>(blockSums, blockOffs, NB, row_start, N, E);
    scan_write<<<NB, 256, 0, stream>>>(deg_in, blockOffs, row_start, cursor, N);

    // 3. fill perm (edge srcs grouped by dst)
    fill_perm<<<(E + 255) / 256, 256, 0, stream>>>(src, dst, cursor, perm, E);

    // 4. degrees -> norms (in place; AFTER scan_write consumed int deg_in)
    norm_finalize<<<(N + 255) / 256, 256, 0, stream>>>(deg_out, norm_out, N);
    norm_finalize<<<(N + 255) / 256, 256, 0, stream>>>(deg_in, norm_in, N);

    // 5. layer-1 aggregation (gather)
    gather_agg128<<<(N + 3) / 4, 256, 0, stream>>>(h, perm, row_start, norm_out, agg1, N);

    // 6. layer-1 projection + epilogue
    gemm_tiled<0><<<dim3((N + 63) / 64, HID / 64), 256, 0, stream>>>(
        agg1, W1, h1n, N, IN, HID, norm_in, norm_out, b1);

    // 7. layer-2 projection
    gemm_tiled<1><<<dim3((N + 63) / 64, OUT / 64), 256, 0, stream>>>(
        h1n, W2, h2, N, HID, OUT, nullptr, nullptr, nullptr);

    // 8. layer-2 aggregation + fused epilogue -> d_out
    gather_out64<<<(N + 3) / 4, 256, 0, stream>>>(h2, perm, row_start, norm_in, b2, out, N);
}

// Round 5
// 661.751 us; speedup vs baseline: 6.7577x; 1.1366x over previous
//
#include <hip/hip_runtime.h>

// ---------------------------------------------------------------------------
// GCN 2-layer forward, f32 — CSR-gather, float4 gathers, 8x8 FMA GEMM.
// ---------------------------------------------------------------------------

__global__ __launch_bounds__(256)
void hist_int(const int* __restrict__ src, const int* __restrict__ dst,
              int* __restrict__ deg_out, int* __restrict__ deg_in, int E)
{
    int e = blockIdx.x * 256 + threadIdx.x;
    if (e < E) {
        atomicAdd(&deg_out[src[e]], 1);
        atomicAdd(&deg_in[dst[e]], 1);
    }
}

// ---- 3-kernel exclusive scan over deg_in (chunk = 1024 elems/block) -------
__global__ __launch_bounds__(256)
void scan_block_sums(const int* __restrict__ deg, int* __restrict__ blockSums, int N)
{
    int t = threadIdx.x;
    int base = blockIdx.x * 1024 + t * 4;
    int s = 0;
    #pragma unroll
    for (int i = 0; i < 4; ++i) { int idx = base + i; if (idx < N) s += deg[idx]; }
    #pragma unroll
    for (int d = 32; d > 0; d >>= 1) s += __shfl_down(s, d);
    __shared__ int ws[4];
    int wid = t >> 6, lane = t & 63;
    if (lane == 0) ws[wid] = s;
    __syncthreads();
    if (t == 0) blockSums[blockIdx.x] = ws[0] + ws[1] + ws[2] + ws[3];
}

__global__ void scan_offsets(const int* __restrict__ blockSums, int* __restrict__ blockOffs,
                             int NB, int* __restrict__ row_start, int N, int E)
{
    if (threadIdx.x == 0 && blockIdx.x == 0) {
        int run = 0;
        for (int b = 0; b < NB; ++b) { blockOffs[b] = run; run += blockSums[b]; }
        row_start[N] = E;
    }
}

__global__ __launch_bounds__(256)
void scan_write(const int* __restrict__ deg, const int* __restrict__ blockOffs,
                int* __restrict__ row_start, int* __restrict__ cursor, int N)
{
    int t = threadIdx.x, lane = t & 63, wid = t >> 6;
    int base = blockIdx.x * 1024 + t * 4;
    int v[4]; int s = 0;
    #pragma unroll
    for (int i = 0; i < 4; ++i) {
        int idx = base + i;
        v[i] = (idx < N) ? deg[idx] : 0;
        s += v[i];
    }
    int x = s;
    #pragma unroll
    for (int d = 1; d < 64; d <<= 1) { int y = __shfl_up(x, d); if (lane >= d) x += y; }
    __shared__ int wtot[4];
    if (lane == 63) wtot[wid] = x;
    __syncthreads();
    int woff = 0;
    for (int w = 0; w < wid; ++w) woff += wtot[w];
    int run = (x - s) + woff + blockOffs[blockIdx.x];
    #pragma unroll
    for (int i = 0; i < 4; ++i) {
        int idx = base + i;
        if (idx < N) { row_start[idx] = run; cursor[idx] = run; run += v[i]; }
    }
}

__global__ __launch_bounds__(256)
void fill_perm(const int* __restrict__ src, const int* __restrict__ dst,
               int* __restrict__ cursor, int* __restrict__ perm, int E)
{
    int e = blockIdx.x * 256 + threadIdx.x;
    if (e < E) {
        int pos = atomicAdd(&cursor[dst[e]], 1);
        perm[pos] = src[e];
    }
}

__global__ __launch_bounds__(256)
void norm_finalize(int* __restrict__ deg, float* __restrict__ nrm, int n)
{
    int i = blockIdx.x * 256 + threadIdx.x;
    if (i < n) {
        int d = deg[i];
        float df = (float)(d > 1 ? d : 1);
        nrm[i] = 1.0f / sqrtf(df);
    }
}

// 128-ch gather: half-wave (32 lanes) x float4 covers one 512B row.
// Wave processes 2 edges per step (4 with unroll); halves combined by shfl.
__global__ __launch_bounds__(256)
void gather_agg128(const float* __restrict__ X, const int* __restrict__ perm,
                   const int* __restrict__ row_start, const float* __restrict__ norm_out,
                   float* __restrict__ out, int N)
{
    int wid = threadIdx.x >> 6, lane = threadIdx.x & 63;
    int n = blockIdx.x * 4 + wid;
    if (n >= N) return;
    int half = lane >> 5;
    int sub  = lane & 31;
    const float4* X4 = (const float4*)X;
    int e = row_start[n], e1 = row_start[n + 1];
    float4 acc = make_float4(0.f, 0.f, 0.f, 0.f);

    for (; e + 4 <= e1; e += 4) {
        int a = perm[e + half];
        int b = perm[e + 2 + half];
        float wa = norm_out[a], wb = norm_out[b];
        float4 va = X4[(size_t)a * 32 + sub];
        float4 vb = X4[(size_t)b * 32 + sub];
        acc.x = fmaf(va.x, wa, fmaf(vb.x, wb, acc.x));
        acc.y = fmaf(va.y, wa, fmaf(vb.y, wb, acc.y));
        acc.z = fmaf(va.z, wa, fmaf(vb.z, wb, acc.z));
        acc.w = fmaf(va.w, wa, fmaf(vb.w, wb, acc.w));
    }
    for (; e + 2 <= e1; e += 2) {
        int a = perm[e + half];
        float wa = norm_out[a];
        float4 va = X4[(size_t)a * 32 + sub];
        acc.x = fmaf(va.x, wa, acc.x);
        acc.y = fmaf(va.y, wa, acc.y);
        acc.z = fmaf(va.z, wa, acc.z);
        acc.w = fmaf(va.w, wa, acc.w);
    }
    if (e < e1 && half == 0) {
        int a = perm[e];
        float wa = norm_out[a];
        float4 va = X4[(size_t)a * 32 + sub];
        acc.x = fmaf(va.x, wa, acc.x);
        acc.y = fmaf(va.y, wa, acc.y);
        acc.z = fmaf(va.z, wa, acc.z);
        acc.w = fmaf(va.w, wa, acc.w);
    }
    acc.x += __shfl_xor(acc.x, 32);
    acc.y += __shfl_xor(acc.y, 32);
    acc.z += __shfl_xor(acc.z, 32);
    acc.w += __shfl_xor(acc.w, 32);
    if (half == 0)
        ((float4*)out)[(size_t)n * 32 + sub] = acc;
}

// 64-ch gather: quarter-wave (16 lanes) x float4 covers one 256B row.
// Wave processes 4 edges per step (8 with unroll); fused *norm_in + bias.
__global__ __launch_bounds__(256)
void gather_out64(const float* __restrict__ X, const int* __restrict__ perm,
                  const int* __restrict__ row_start, const float* __restrict__ norm_in,
                  const float* __restrict__ bias, float* __restrict__ out, int N)
{
    int wid = threadIdx.x >> 6, lane = threadIdx.x & 63;
    int n = blockIdx.x * 4 + wid;
    if (n >= N) return;
    int q   = lane >> 4;
    int sub = lane & 15;
    const float4* X4 = (const float4*)X;
    int e = row_start[n], e1 = row_start[n + 1];
    float4 acc = make_float4(0.f, 0.f, 0.f, 0.f);

    for (; e + 8 <= e1; e += 8) {
        int a = perm[e + q];
        int b = perm[e + 4 + q];
        float4 va = X4[(size_t)a * 16 + sub];
        float4 vb = X4[(size_t)b * 16 + sub];
        acc.x += va.x + vb.x;
        acc.y += va.y + vb.y;
        acc.z += va.z + vb.z;
        acc.w += va.w + vb.w;
    }
    for (; e + 4 <= e1; e += 4) {
        int a = perm[e + q];
        float4 va = X4[(size_t)a * 16 + sub];
        acc.x += va.x; acc.y += va.y; acc.z += va.z; acc.w += va.w;
    }
    int r = e1 - e;      // 0..3
    if (q < r) {
        int a = perm[e + q];
        float4 va = X4[(size_t)a * 16 + sub];
        acc.x += va.x; acc.y += va.y; acc.z += va.z; acc.w += va.w;
    }
    acc.x += __shfl_xor(acc.x, 32);
    acc.y += __shfl_xor(acc.y, 32);
    acc.z += __shfl_xor(acc.z, 32);
    acc.w += __shfl_xor(acc.w, 32);
    acc.x += __shfl_xor(acc.x, 16);
    acc.y += __shfl_xor(acc.y, 16);
    acc.z += __shfl_xor(acc.z, 16);
    acc.w += __shfl_xor(acc.w, 16);
    if (q == 0) {
        float ni = norm_in[n];
        float4 bv = ((const float4*)bias)[sub];
        float4 o;
        o.x = fmaf(acc.x, ni, bv.x);
        o.y = fmaf(acc.y, ni, bv.y);
        o.z = fmaf(acc.z, ni, bv.z);
        o.w = fmaf(acc.w, ni, bv.w);
        ((float4*)out)[(size_t)n * 16 + sub] = o;
    }
}

// Tiled f32 GEMM: C[M,NC] = A[M,K]@B[K,NC]. BM=128, BK=16, 256 thr.
// BN=128 -> 8x8/thr, BN=64 -> 8x4/thr. 2 FLOP per LDS byte -> FMA-bound.
// EPI==0: C = relu(C*norm_in[row]+bias[col])*norm_out[row]; EPI==1: plain.
template<int BN, int TN, int EPI>
__global__ __launch_bounds__(256)
void gemm_tiled(const float* __restrict__ A, const float* __restrict__ B,
                float* __restrict__ C, int M, int K, int NC,
                const float* __restrict__ norm_in,
                const float* __restrict__ norm_out,
                const float* __restrict__ bias)
{
    __shared__ float As[16][132];   // [k][m], padded
    __shared__ float Bs[16][BN];    // [k][n]
    const int tid = threadIdx.x;
    const int tx = tid & 15;        // col group (TN cols)
    const int ty = tid >> 4;        // row group (8 rows)
    const int brow = blockIdx.x * 128;
    const int bcol = blockIdx.y * BN;

    const int ar = tid >> 2;        // 0..63
    const int ak = (tid & 3) * 4;   // 0,4,8,12

    float acc[8][TN] = {};

    for (int k0 = 0; k0 < K; k0 += 16) {
        // stage A (transpose into LDS): rows ar, ar+64
        #pragma unroll
        for (int hh = 0; hh < 2; ++hh) {
            int row = ar + hh * 64;
            int grow = brow + row;
            float4 v = make_float4(0.f, 0.f, 0.f, 0.f);
            if (grow < M) v = *(const float4*)(A + (size_t)grow * K + k0 + ak);
            As[ak + 0][row] = v.x;
            As[ak + 1][row] = v.y;
            As[ak + 2][row] = v.z;
            As[ak + 3][row] = v.w;
        }
        // stage B (direct)
        if (BN == 128) {
            #pragma unroll
            for (int hh = 0; hh < 2; ++hh) {
                int kr = (tid >> 5) + hh * 8;
                int cc = (tid & 31) * 4;
                *(float4*)&Bs[kr][cc] =
                    *(const float4*)(B + (size_t)(k0 + kr) * NC + bcol + cc);
            }
        } else {
            int kr = tid >> 4;
            int cc = (tid & 15) * 4;
            *(float4*)&Bs[kr][cc] =
                *(const float4*)(B + (size_t)(k0 + kr) * NC + bcol + cc);
        }
        __syncthreads();
        #pragma unroll
        for (int k = 0; k < 16; ++k) {
            float a0[8], b0[TN];
            *(float4*)&a0[0] = *(const float4*)&As[k][ty * 8];
            *(float4*)&a0[4] = *(const float4*)&As[k][ty * 8 + 4];
            *(float4*)&b0[0] = *(const float4*)&Bs[k][tx * TN];
            if (TN == 8)
                *(float4*)&b0[4] = *(const float4*)&Bs[k][tx * TN + 4];
            #pragma unroll
            for (int i = 0; i < 8; ++i)
                #pragma unroll
                for (int j = 0; j < TN; ++j)
                    acc[i][j] = fmaf(a0[i], b0[j], acc[i][j]);
        }
        __syncthreads();
    }

    #pragma unroll
    for (int i = 0; i < 8; ++i) {
        int row = brow + ty * 8 + i;
        if (row >= M) continue;
        float ni = 0.f, no = 0.f;
        if (EPI == 0) { ni = norm_in[row]; no = norm_out[row]; }
        #pragma unroll
        for (int j4 = 0; j4 < TN; j4 += 4) {
            int col = bcol + tx * TN + j4;
            float4 o = *(float4*)&acc[i][j4];
            if (EPI == 0) {
                o.x = fmaxf(fmaf(o.x, ni, bias[col + 0]), 0.0f) * no;
                o.y = fmaxf(fmaf(o.y, ni, bias[col + 1]), 0.0f) * no;
                o.z = fmaxf(fmaf(o.z, ni, bias[col + 2]), 0.0f) * no;
                o.w = fmaxf(fmaf(o.w, ni, bias[col + 3]), 0.0f) * no;
            }
            *(float4*)(C + (size_t)row * NC + col) = o;
        }
    }
}

extern "C" void kernel_launch(void* const* d_in, const int* in_sizes, int n_in,
                              void* d_out, int out_size, void* d_ws, size_t ws_size,
                              hipStream_t stream)
{
    const float* h   = (const float*)d_in[0];
    const int*   src = (const int*)d_in[1];
    const int*   dst = (const int*)d_in[2];
    const float* W1  = (const float*)d_in[3];
    const float* b1  = (const float*)d_in[4];
    const float* W2  = (const float*)d_in[5];
    const float* b2  = (const float*)d_in[6];
    float* out = (float*)d_out;

    const int HID = in_sizes[4];            // 256
    const int OUT = in_sizes[6];            // 64
    const int IN  = in_sizes[3] / HID;      // 128
    const int N   = in_sizes[0] / IN;       // 100000
    const int E   = in_sizes[1];            // 1600000
    const int NB  = (N + 1023) / 1024;

    char* p = (char*)d_ws;
    auto alloc = [&](size_t bytes) { void* r = p; p += (bytes + 255) & ~255ULL; return r; };
    int* deg_out   = (int*)alloc((size_t)N * 4);
    int* deg_in    = (int*)alloc((size_t)N * 4);
    int* row_start = (int*)alloc((size_t)(N + 1) * 4);
    int* cursor    = (int*)alloc((size_t)N * 4);
    int* blockSums = (int*)alloc((size_t)NB * 4);
    int* blockOffs = (int*)alloc((size_t)NB * 4);
    int* perm      = (int*)alloc((size_t)E * 4);
    float* agg1    = (float*)alloc((size_t)N * IN * 4);
    float* h1n     = (float*)alloc((size_t)N * HID * 4);
    float* h2      = agg1;
    float* norm_out = (float*)deg_out;
    float* norm_in  = (float*)deg_in;

    hipMemsetAsync(deg_out, 0, (size_t)((char*)row_start - (char*)deg_out), stream);

    hist_int<<<(E + 255) / 256, 256, 0, stream>>>(src, dst, deg_out, deg_in, E);

    scan_block_sums<<<NB, 256, 0, stream>>>(deg_in, blockSums, N);
    scan_offsets<<<1, 64, 0, stream>>>(blockSums, blockOffs, NB, row_start, N, E);
    scan_write<<<NB, 256, 0, stream>>>(deg_in, blockOffs, row_start, cursor, N);

    fill_perm<<<(E + 255) / 256, 256, 0, stream>>>(src, dst, cursor, perm, E);

    norm_finalize<<<(N + 255) / 256, 256, 0, stream>>>(deg_out, norm_out, N);
    norm_finalize<<<(N + 255) / 256, 256, 0, stream>>>(deg_in, norm_in, N);

    gather_agg128<<<(N + 3) / 4, 256, 0, stream>>>(h, perm, row_start, norm_out, agg1, N);

    gemm_tiled<128, 8, 0><<<dim3((N + 127) / 128, HID / 128), 256, 0, stream>>>(
        agg1, W1, h1n, N, IN, HID, norm_in, norm_out, b1);

    gemm_tiled<64, 4, 1><<<dim3((N + 127) / 128, OUT / 64), 256, 0, stream>>>(
        h1n, W2, h2, N, HID, OUT, nullptr, nullptr, nullptr);

    gather_out64<<<(N + 3) / 4, 256, 0, stream>>>(h2, perm, row_start, norm_in, b2, out, N);
}